// Round 1
// 477.824 us; speedup vs baseline: 1.0964x; 1.0964x over previous
//
#include <hip/hip_runtime.h>
#include <stdint.h>

#define T_FULL 2049
#define T_OUT  2048
#define NB     256
#define ND     128
#define U_DIM  32768      // NB*ND
#define NT_BLK 8          // t per gemm block
#define NPART  (T_OUT / NT_BLK)   // 256 partials, one per block

typedef __bf16 bf16x8 __attribute__((ext_vector_type(8)));
typedef float  f32x4  __attribute__((ext_vector_type(4)));

// async global->LDS. LDS dest = uniform base + lane*size.
__device__ __forceinline__ void gl_lds16(const void* g, void* l) {
  void* gnc = const_cast<void*>(g);
  __builtin_amdgcn_global_load_lds(
      (__attribute__((address_space(1))) unsigned int*)gnc,
      (__attribute__((address_space(3))) unsigned int*)l, 16, 0, 0);
}

// ---------------------------------------------------------------------------
// Kernel 1 v6 (unchanged): transpose to bf16 via VGPR staging.
// Block = 64u x 64t, LDS 64x65 fp32 -> ~8 blocks/CU. 64-B read segments,
// 128-B write segments, LDS reads exactly 2-way (free, m136).
// ---------------------------------------------------------------------------
#define TP 65
__global__ __launch_bounds__(256) void transpose_split(
    const float* __restrict__ pred, __bf16* __restrict__ H) {
  __shared__ __align__(16) float tile[64 * TP];
  const int u0 = blockIdx.x << 6;   // 64 u per block
  const int t0 = blockIdx.y << 6;   // 64 t per block (t0+63 <= 2047)
  const int tid  = threadIdx.x;
  const int w    = tid >> 6;
  const int l    = tid & 63;

  const int r  = (w << 4) + (l >> 2);
  const int c0 = l & 3;
  const float* src = pred + (size_t)(u0 + r) * T_FULL + t0 + (c0 << 2);
  float4 v[4];
#pragma unroll
  for (int i = 0; i < 4; ++i) v[i] = *(const float4*)(src + (i << 4));
#pragma unroll
  for (int i = 0; i < 4; ++i)
    *(float4*)&tile[r * TP + (c0 << 2) + (i << 4)] = v[i];
  __syncthreads();

  const int uc = (l & 7) << 3;
#pragma unroll
  for (int p = 0; p < 2; ++p) {
    const int tl = (w << 4) + (p << 3) + (l >> 3);
    float x[8];
#pragma unroll
    for (int k = 0; k < 8; ++k) x[k] = tile[(uc + k) * TP + tl];
    bf16x8 hv;
#pragma unroll
    for (int k = 0; k < 8; ++k) hv[k] = (__bf16)x[k];
    *(bf16x8*)(H + (size_t)(t0 + tl) * U_DIM + u0 + uc) = hv;
  }
}

// tail: the t = 2048 slice (stride-2049 scalar reads, 32768 elements)
__global__ __launch_bounds__(256) void transpose_tail(
    const float* __restrict__ pred, __bf16* __restrict__ H) {
  const int u = (blockIdx.x << 8) + threadIdx.x;
  H[(size_t)T_OUT * U_DIM + u] = (__bf16)pred[(size_t)u * T_FULL + T_OUT];
}

// ---------------------------------------------------------------------------
// Kernel 2 v5: sliding-t persistent blocks. Grid = 256 blocks (1/CU), 512
// threads (8 waves). Each block owns 8 consecutive t; slices double-buffered
// in 2 x 64 KB LDS with the chunk-XOR swizzle (chunk cg = cst ^ (row&7)).
// Per t: A-frags -> regs from buf[t&1], barrier, prefetch slice t+2 into
// buf[t&1] (overlaps MFMA), MFMA B from buf[(t+1)&1], in-register LSE.
// Wave tile = 32 rows x 256 cols (rows w*32..w*32+31), so the row-reduce
// is wave-local: shfl_xor over the 4 low lane bits (col lanes).
// Traffic: ~9 slices * 64 KB per block = 144 MB total (vs 671 MB before).
// ---------------------------------------------------------------------------
__global__ __launch_bounds__(512, 2) void gemm_lse_sliding(
    const __bf16* __restrict__ H, float* __restrict__ partials) {
  __shared__ __align__(16) char lds[131072];   // 2 x 64 KB slice buffers

  const int tid  = threadIdx.x;
  const int w    = tid >> 6;     // wave 0..7 -> rows w*32..w*32+31
  const int lane = tid & 63;
  const int q    = lane >> 4;    // 0..3
  const int rr   = lane & 15;    // output col within tile
  const int e    = rr & 7;       // swizzle key
  const int t0   = blockIdx.x << 3;

  // ---- stage one 64 KB slice into buffer bs (0/1): 8 gl_lds16 per lane ----
  auto stage = [&](int slice, int bs) {
    char* dst = lds + (bs << 16);
    const __bf16* src = H + (size_t)slice * U_DIM;
    const int srow4 = lane >> 4;
    const int cst   = lane & 15;
#pragma unroll
    for (int i2 = 0; i2 < 8; ++i2) {
      const int g   = (w << 3) + i2;        // 4-row group 0..63
      const int row = (g << 2) + srow4;
      const int cg  = cst ^ (row & 7);      // global chunk to fetch
      gl_lds16(src + (size_t)row * ND + (cg << 3), dst + (g << 10));
    }
  };

  stage(t0, 0);
  stage(t0 + 1, 1);
  __syncthreads();   // drains both prologue stages

  float lsum = 0.f;
  const int arow0 = (w << 5) + rr;   // A row for rt=0 (rt=1: +16)

  for (int i = 0; i < NT_BLK; ++i) {
    const int pa = i & 1;

    // ---- A fragments -> registers from buf[pa] (slice t0+i) ----
    bf16x8 af[2][4];
    {
      const char* As = lds + (pa << 16);
#pragma unroll
      for (int rt = 0; rt < 2; ++rt) {
        const char* ap = As + (arow0 + (rt << 4)) * 256;
#pragma unroll
        for (int ks = 0; ks < 4; ++ks) {
          const int cix = ((ks << 2) + q) ^ e;
          af[rt][ks] = *(const bf16x8*)(ap + (cix << 4));
        }
      }
    }
    __syncthreads();   // all waves' A reads done; prior prefetch drained

    // ---- prefetch slice t0+i+2 into buf[pa]; overlaps MFMA below ----
    if (i < NT_BLK - 2) stage(t0 + i + 2, pa);

    // ---- MFMA: S[32 rows][256 cols], B = slice t0+i+1 in buf[pa^1] ----
    f32x4 acc[2][16];
#pragma unroll
    for (int rt = 0; rt < 2; ++rt)
#pragma unroll
      for (int ct = 0; ct < 16; ++ct) acc[rt][ct] = f32x4{0.f, 0.f, 0.f, 0.f};

    const __bf16* Bs = (const __bf16*)(lds + ((pa ^ 1) << 16));
#pragma unroll
    for (int ks = 0; ks < 4; ++ks) {
      const int cix = ((ks << 2) + q) ^ e;
      const __bf16* bp = Bs + (size_t)rr * ND + (cix << 3);
#pragma unroll
      for (int ct = 0; ct < 16; ++ct) {
        const bf16x8 bv = *(const bf16x8*)(bp + (ct << 11));  // ct*16 rows
        acc[0][ct] = __builtin_amdgcn_mfma_f32_16x16x32_bf16(af[0][ks], bv, acc[0][ct], 0, 0, 0);
        acc[1][ct] = __builtin_amdgcn_mfma_f32_16x16x32_bf16(af[1][ks], bv, acc[1][ct], 0, 0, 0);
      }
    }

    // ---- in-register LSE. Lane holds rows {w*32+rt*16+q*4+r}, col ct*16+rr.
    float mx[2][4], pp[2][4];
#pragma unroll
    for (int rt = 0; rt < 2; ++rt)
#pragma unroll
      for (int r = 0; r < 4; ++r) mx[rt][r] = -3.0e38f;
#pragma unroll
    for (int rt = 0; rt < 2; ++rt)
#pragma unroll
      for (int ct = 0; ct < 16; ++ct)
#pragma unroll
        for (int r = 0; r < 4; ++r) mx[rt][r] = fmaxf(mx[rt][r], acc[rt][ct][r]);
#pragma unroll
    for (int off = 1; off < 16; off <<= 1)
#pragma unroll
      for (int rt = 0; rt < 2; ++rt)
#pragma unroll
        for (int r = 0; r < 4; ++r)
          mx[rt][r] = fmaxf(mx[rt][r], __shfl_xor(mx[rt][r], off, 64));

#pragma unroll
    for (int rt = 0; rt < 2; ++rt)
#pragma unroll
      for (int r = 0; r < 4; ++r) pp[rt][r] = 0.f;
#pragma unroll
    for (int rt = 0; rt < 2; ++rt)
#pragma unroll
      for (int ct = 0; ct < 16; ++ct)
#pragma unroll
        for (int r = 0; r < 4; ++r)
          pp[rt][r] += __expf(acc[rt][ct][r] - mx[rt][r]);
#pragma unroll
    for (int off = 1; off < 16; off <<= 1)
#pragma unroll
      for (int rt = 0; rt < 2; ++rt)
#pragma unroll
        for (int r = 0; r < 4; ++r) pp[rt][r] += __shfl_xor(pp[rt][r], off, 64);

    // diag row == col: ct = w*2+rt, rr = q*4+r. Each row claimed by exactly
    // one lane (rr>>2 == q, r = rr&3). All indices compile-time (rule #20).
#pragma unroll
    for (int rt = 0; rt < 2; ++rt)
#pragma unroll
      for (int r = 0; r < 4; ++r)
        if (rr == (q << 2) + r) {
          float dv = 0.f;
#pragma unroll
          for (int ct = 0; ct < 16; ++ct)
            if (ct == (w << 1) + rt) dv = acc[rt][ct][r];
          lsum += (mx[rt][r] - dv) + logf(pp[rt][r]);
        }
  }

  // ---- block reduction: wave shfl-sum -> LDS -> thread 0 ----
#pragma unroll
  for (int off = 1; off < 64; off <<= 1) lsum += __shfl_xor(lsum, off, 64);
  __syncthreads();   // all slice-buffer traffic done; reuse LDS as scratch
  float* red = (float*)lds;
  if (lane == 0) red[w] = lsum;
  __syncthreads();
  if (tid == 0) {
    float s = 0.f;
#pragma unroll
    for (int k = 0; k < 8; ++k) s += red[k];
    partials[blockIdx.x] = s;
  }
}

// ---------------------------------------------------------------------------
// Kernel 3: deterministic reduction of NPART partials in fp64, scale 1/(T*B)
// ---------------------------------------------------------------------------
__global__ __launch_bounds__(256) void final_reduce(
    const float* __restrict__ partials, float* __restrict__ out) {
  __shared__ double sh[256];
  double s = 0.0;
  for (int i = threadIdx.x; i < NPART; i += 256) s += (double)partials[i];
  sh[threadIdx.x] = s;
  __syncthreads();
  for (int st = 128; st > 0; st >>= 1) {
    if ((int)threadIdx.x < st) sh[threadIdx.x] += sh[threadIdx.x + st];
    __syncthreads();
  }
  if (threadIdx.x == 0) out[0] = (float)(sh[0] * (1.0 / ((double)T_OUT * NB)));
}

extern "C" void kernel_launch(void* const* d_in, const int* in_sizes, int n_in,
                              void* d_out, int out_size, void* d_ws, size_t ws_size,
                              hipStream_t stream) {
  const float* pred = (const float*)d_in[0];
  float* out = (float*)d_out;
  char* ws = (char*)d_ws;
  __bf16* H = (__bf16*)ws;                                      // 134.3 MB
  float* partials = (float*)(ws + (size_t)T_FULL * U_DIM * 2);  // 1 KB

  dim3 tgrid(U_DIM / 64, T_OUT / 64);  // t in [0,2048)
  transpose_split<<<tgrid, 256, 0, stream>>>(pred, H);
  transpose_tail<<<U_DIM / 256, 256, 0, stream>>>(pred, H);
  gemm_lse_sliding<<<NPART, 512, 0, stream>>>(H, partials);
  final_reduce<<<1, 256, 0, stream>>>(partials, out);
}